// Round 11
// baseline (539.542 us; speedup 1.0000x reference)
//
#include <hip/hip_runtime.h>

// Problem dims
#define B_DIM 64
#define IN_CH 16
#define H_DIM 256
#define FDIM  128
#define NF    1001
#define INS0  144      // FDIM + IN_CH
#define TB    7        // timesteps per block in prep gf-role (1001 = 7*143)
#define NEP   144      // 144 epochs x 7 = 1008 steps (covers k=0..1007)
#define GF_BLOCKS 143

// Gate pre-activations are PRE-SCALED so they feed v_exp_f32 (exp2) directly:
//   rows i,f,o:  scale = -log2(e)    -> exp2(arg) = e^{-gate}
//   row  g:      scale = -2*log2(e)  -> exp2(arg) = e^{-2*gate}
#define SC_IFO (-1.44269504088896340736f)
#define SC_G   (-2.88539008177792681472f)

__device__ __forceinline__ float gate_scale(int j) {
    return (j >= 512 && j < 768) ? SC_G : SC_IFO;
}
__device__ __forceinline__ float gsc(int g) { return (g == 2) ? SC_G : SC_IFO; }

// ---------------------------------------------------------------------------
// Light barrier: wave-local LDS drain + raw s_barrier. Unlike __syncthreads
// this does NOT force vmcnt(0) — global prefetches/stores stay in flight
// across steps (the r8 structure's 800cy/step killer).
// ---------------------------------------------------------------------------
__device__ __forceinline__ void fast_barrier() {
    asm volatile("s_waitcnt lgkmcnt(0)" ::: "memory");
    __builtin_amdgcn_s_barrier();
}

// ---------------------------------------------------------------------------
// Wave64 sum-reduce via DPP; full sum lands in lane 63 (lane 63 is the LDS
// writer, no readlane needed).
// ---------------------------------------------------------------------------
template<int CTRL, int ROW_MASK>
__device__ __forceinline__ float dpp_add(float x) {
    int y = __builtin_amdgcn_update_dpp(0, __float_as_int(x), CTRL, ROW_MASK, 0xf, true);
    return x + __int_as_float(y);
}
__device__ __forceinline__ float reduce63(float x) {
    x = dpp_add<0x111, 0xf>(x);   // row_shr:1
    x = dpp_add<0x112, 0xf>(x);   // row_shr:2
    x = dpp_add<0x114, 0xf>(x);   // row_shr:4
    x = dpp_add<0x118, 0xf>(x);   // row_shr:8
    x = dpp_add<0x142, 0xa>(x);   // row_bcast:15 into rows 1,3
    x = dpp_add<0x143, 0xc>(x);   // row_bcast:31 into rows 2,3
    return x;                      // lane 63 holds the 64-lane sum
}

// ---------------------------------------------------------------------------
// Merged prep kernel. Blocks [0,143): Gf[t][j] = (f[t]·Wih0[j][:128])*scale(j).
// Blocks [143,207): Gxb[b][j] = (x[b]·Wih0[j][128:] + bih0[j]+bhh0[j])*scale(j).
// ---------------------------------------------------------------------------
__global__ __launch_bounds__(1024) void prep_kernel(
    const float* __restrict__ f, const float* __restrict__ x,
    const float* __restrict__ W,
    const float* __restrict__ bih, const float* __restrict__ bhh,
    float* __restrict__ Gf, float* __restrict__ Gxb)
{
    const int tid = threadIdx.x;
    const int j = tid;
    if (blockIdx.x < GF_BLOCKS) {
        __shared__ float fs[TB][FDIM];
        const int t0 = blockIdx.x * TB;
        for (int i = tid; i < TB * FDIM; i += 1024)
            fs[i >> 7][i & 127] = f[t0 * FDIM + i];
        __syncthreads();

        const float4* w4 = (const float4*)(W + j * INS0);
        float acc[TB];
#pragma unroll
        for (int t = 0; t < TB; ++t) acc[t] = 0.f;
#pragma unroll
        for (int kc = 0; kc < 8; ++kc) {
            float4 a = w4[kc * 4 + 0];
            float4 b = w4[kc * 4 + 1];
            float4 c = w4[kc * 4 + 2];
            float4 d = w4[kc * 4 + 3];
#pragma unroll
            for (int t = 0; t < TB; ++t) {
                const float* fp = &fs[t][kc * 16];
                float s = acc[t];
                s = fmaf(a.x, fp[0], s);  s = fmaf(a.y, fp[1], s);
                s = fmaf(a.z, fp[2], s);  s = fmaf(a.w, fp[3], s);
                s = fmaf(b.x, fp[4], s);  s = fmaf(b.y, fp[5], s);
                s = fmaf(b.z, fp[6], s);  s = fmaf(b.w, fp[7], s);
                s = fmaf(c.x, fp[8], s);  s = fmaf(c.y, fp[9], s);
                s = fmaf(c.z, fp[10], s); s = fmaf(c.w, fp[11], s);
                s = fmaf(d.x, fp[12], s); s = fmaf(d.y, fp[13], s);
                s = fmaf(d.z, fp[14], s); s = fmaf(d.w, fp[15], s);
                acc[t] = s;
            }
        }
        const float sc = gate_scale(j);
#pragma unroll
        for (int t = 0; t < TB; ++t)
            Gf[(size_t)(t0 + t) * 1024 + j] = acc[t] * sc;
    } else {
        const int b = blockIdx.x - GF_BLOCKS;
        const float* w = W + j * INS0 + FDIM;
        const float* xb = x + b * IN_CH;
        float s = bih[j] + bhh[j];
#pragma unroll
        for (int k = 0; k < IN_CH; ++k) s = fmaf(xb[k], w[k], s);
        Gxb[b * 1024 + j] = s * gate_scale(j);
    }
}

// ---------------------------------------------------------------------------
// Gf gate quad for unit j0 at timestep t: (i,f,g,o) pre-scaled.
// ---------------------------------------------------------------------------
__device__ __forceinline__ float4 ldgate(const float* __restrict__ Gf, int t, int j0) {
    const float* p = Gf + (size_t)t * 1024 + j0;
    float4 r; r.x = p[0]; r.y = p[256]; r.z = p[512]; r.w = p[768];
    return r;
}

// ---------------------------------------------------------------------------
// One recurrent step for one wave (1 hidden unit per lane). Reads own-group
// partials (h_{t-1}) and upstream partials from LDS, computes the unit,
// DPP-reduces the projection partial, lane 63 writes it to LDS.
// ---------------------------------------------------------------------------
__device__ __forceinline__ float step_fn(
    int k, float4 gv, int lay, int lane, int q,
    const float whh[4], const float wih[4], const float base[4], float whr0,
    float& c, float4 (*part4)[2])
{
    const int pr = (k - 1) & 1;
    float4 own = part4[lay][pr];
    float h = (own.x + own.y) + (own.z + own.w);
    const bool active = (k >= lay) && (k < NF + lay);
    if (active) {
        float pre0, pre1, pre2, pre3;
        if (lay == 0) {
            pre0 = gv.x + base[0]; pre1 = gv.y + base[1];
            pre2 = gv.z + base[2]; pre3 = gv.w + base[3];
        } else {
            float4 up = part4[lay - 1][pr];
            float hin = (up.x + up.y) + (up.z + up.w);
            pre0 = fmaf(hin, wih[0], base[0]);
            pre1 = fmaf(hin, wih[1], base[1]);
            pre2 = fmaf(hin, wih[2], base[2]);
            pre3 = fmaf(hin, wih[3], base[3]);
        }
        float gi = fmaf(h, whh[0], pre0);
        float gf_ = fmaf(h, whh[1], pre1);
        float gg = fmaf(h, whh[2], pre2);
        float go = fmaf(h, whh[3], pre3);
        float A  = __builtin_amdgcn_exp2f(gi);    // e^-gi
        float Dv = __builtin_amdgcn_exp2f(gf_);   // e^-gf
        float Bv = __builtin_amdgcn_exp2f(gg);    // e^-2gg
        float Fv = __builtin_amdgcn_exp2f(go);    // e^-go
        float a1 = 1.f + A, b1 = 1.f + Bv, d1 = 1.f + Dv, f1 = 1.f + Fv;
        float p1 = a1 * b1;
        float r1 = __builtin_amdgcn_rcpf(p1 * d1);
        float si_tg = (1.f - Bv) * d1 * r1;       // sigmoid(gi)*tanh(gg)
        float sf    = p1 * r1;                    // sigmoid(gf)
        c = fmaf(sf, c, si_tg);
        float Cv = __builtin_amdgcn_exp2f(SC_G * c);  // e^-2c
        float r2 = __builtin_amdgcn_rcpf(f1 * (1.f + Cv));
        float hr = (1.f - Cv) * r2;               // sigmoid(go)*tanh(c)
        float m = reduce63(hr * whr0);
        if (lane == 63) ((float*)&part4[lay][k & 1])[q] = m;
    }
    return h;
}

// ---------------------------------------------------------------------------
// Main recurrence. grid = 64 (block = batch), 768 threads = 12 waves:
// lay = wid%3, q = wid/3; each lane owns unit j0 = q*64+lane. Per-step
// fast_barrier (lgkmcnt-only + s_barrier — global loads stay in flight).
// Gf rows register-prefetched one epoch ahead; outputs buffered 7-deep in
// regs, stored once per epoch (stores also uncounted by the barrier).
// ---------------------------------------------------------------------------
__global__ __launch_bounds__(768, 3) void lstm_pipeline(
    const float* __restrict__ Gf, const float* __restrict__ Gxb,
    const float* __restrict__ Whh0, const float* __restrict__ Whr0,
    const float* __restrict__ Wih1, const float* __restrict__ Whh1,
    const float* __restrict__ bih1, const float* __restrict__ bhh1,
    const float* __restrict__ Whr1,
    const float* __restrict__ Wih2, const float* __restrict__ Whh2,
    const float* __restrict__ bih2, const float* __restrict__ bhh2,
    const float* __restrict__ Whr2,
    float* __restrict__ out)
{
    const int b    = blockIdx.x;
    const int wid  = threadIdx.x >> 6;   // 0..11
    const int lane = threadIdx.x & 63;
    const int lay  = wid % 3;            // layer
    const int q    = wid / 3;            // quarter 0..3
    const int j0   = q * 64 + lane;      // hidden unit owned by this lane

    __shared__ float4 part4[3][2];       // [layer][parity]: 4 quarter-partials
    if (threadIdx.x < 24) ((float*)part4)[threadIdx.x] = 0.f;

    const float *whh_p, *whr_p, *wih_p = nullptr, *bi_p = nullptr, *bh_p = nullptr;
    if (lay == 0)      { whh_p = Whh0; whr_p = Whr0; }
    else if (lay == 1) { whh_p = Whh1; whr_p = Whr1; wih_p = Wih1; bi_p = bih1; bh_p = bhh1; }
    else               { whh_p = Whh2; whr_p = Whr2; wih_p = Wih2; bi_p = bih2; bh_p = bhh2; }

    float whh[4], base[4], wih[4];
#pragma unroll
    for (int g = 0; g < 4; ++g)
        whh[g] = whh_p[g * 256 + j0] * gsc(g);
    const float whr0 = whr_p[j0];
    if (lay == 0) {
#pragma unroll
        for (int g = 0; g < 4; ++g) {
            base[g] = Gxb[(size_t)b * 1024 + g * 256 + j0];  // pre-scaled
            wih[g] = 0.f;
        }
    } else {
#pragma unroll
        for (int g = 0; g < 4; ++g) {
            base[g] = (bi_p[g * 256 + j0] + bh_p[g * 256 + j0]) * gsc(g);
            wih[g] = wih_p[g * 256 + j0] * gsc(g);
        }
    }

    // Gf prefetch (layer-0 waves): current epoch u0..u6, next epoch n0..n6.
    float4 u0{}, u1{}, u2{}, u3{}, u4{}, u5{}, u6{};
    float4 n0{}, n1{}, n2{}, n3{}, n4{}, n5{}, n6{};
    if (lay == 0) {
        n0 = ldgate(Gf, 0, j0); n1 = ldgate(Gf, 1, j0); n2 = ldgate(Gf, 2, j0);
        n3 = ldgate(Gf, 3, j0); n4 = ldgate(Gf, 4, j0); n5 = ldgate(Gf, 5, j0);
        n6 = ldgate(Gf, 6, j0);
    }

    float c = 0.f;
    float o0 = 0.f, o1 = 0.f, o2 = 0.f, o3 = 0.f, o4 = 0.f, o5 = 0.f, o6 = 0.f;
    float* outp = out + (size_t)b * NF;
    const bool isStore = (lay == 2) && (q == 0);

    for (int ep = 0; ep < NEP; ++ep) {
        const int k0 = ep * 7;
        float hh;

        fast_barrier();
        if (lay == 0) {
            u0 = n0; u1 = n1; u2 = n2; u3 = n3; u4 = n4; u5 = n5; u6 = n6;
            int tb = k0 + 7;
            n0 = ldgate(Gf, min(tb + 0, NF - 1), j0);
            n1 = ldgate(Gf, min(tb + 1, NF - 1), j0);
            n2 = ldgate(Gf, min(tb + 2, NF - 1), j0);
            n3 = ldgate(Gf, min(tb + 3, NF - 1), j0);
            n4 = ldgate(Gf, min(tb + 4, NF - 1), j0);
            n5 = ldgate(Gf, min(tb + 5, NF - 1), j0);
            n6 = ldgate(Gf, min(tb + 6, NF - 1), j0);
        }
        hh = step_fn(k0 + 0, u0, lay, lane, q, whh, wih, base, whr0, c, part4);
        if (isStore) o0 = hh;
        fast_barrier();
        hh = step_fn(k0 + 1, u1, lay, lane, q, whh, wih, base, whr0, c, part4);
        if (isStore) o1 = hh;
        fast_barrier();
        hh = step_fn(k0 + 2, u2, lay, lane, q, whh, wih, base, whr0, c, part4);
        if (isStore) o2 = hh;
        fast_barrier();
        hh = step_fn(k0 + 3, u3, lay, lane, q, whh, wih, base, whr0, c, part4);
        if (isStore) o3 = hh;
        fast_barrier();
        hh = step_fn(k0 + 4, u4, lay, lane, q, whh, wih, base, whr0, c, part4);
        if (isStore) o4 = hh;
        fast_barrier();
        hh = step_fn(k0 + 5, u5, lay, lane, q, whh, wih, base, whr0, c, part4);
        if (isStore) o5 = hh;
        fast_barrier();
        hh = step_fn(k0 + 6, u6, lay, lane, q, whh, wih, base, whr0, c, part4);
        if (isStore) o6 = hh;

        // h captured at step k is h(t = k-3); store the epoch's 7 values.
        if (isStore && lane == 0) {
            const int tb = k0 - 3;
            if ((unsigned)(tb + 0) < NF) outp[tb + 0] = o0;
            if ((unsigned)(tb + 1) < NF) outp[tb + 1] = o1;
            if ((unsigned)(tb + 2) < NF) outp[tb + 2] = o2;
            if ((unsigned)(tb + 3) < NF) outp[tb + 3] = o3;
            if ((unsigned)(tb + 4) < NF) outp[tb + 4] = o4;
            if ((unsigned)(tb + 5) < NF) outp[tb + 5] = o5;
            if ((unsigned)(tb + 6) < NF) outp[tb + 6] = o6;
        }
    }
}

// ---------------------------------------------------------------------------
extern "C" void kernel_launch(void* const* d_in, const int* in_sizes, int n_in,
                              void* d_out, int out_size, void* d_ws, size_t ws_size,
                              hipStream_t stream)
{
    const float* x    = (const float*)d_in[0];
    const float* f    = (const float*)d_in[1];
    const float* Wih0 = (const float*)d_in[2];
    const float* Whh0 = (const float*)d_in[3];
    const float* bih0 = (const float*)d_in[4];
    const float* bhh0 = (const float*)d_in[5];
    const float* Whr0 = (const float*)d_in[6];
    const float* Wih1 = (const float*)d_in[7];
    const float* Whh1 = (const float*)d_in[8];
    const float* bih1 = (const float*)d_in[9];
    const float* bhh1 = (const float*)d_in[10];
    const float* Whr1 = (const float*)d_in[11];
    const float* Wih2 = (const float*)d_in[12];
    const float* Whh2 = (const float*)d_in[13];
    const float* bih2 = (const float*)d_in[14];
    const float* bhh2 = (const float*)d_in[15];
    const float* Whr2 = (const float*)d_in[16];
    float* out = (float*)d_out;

    float* Gf  = (float*)d_ws;                       // NF * 1024 floats (4.1 MB)
    float* Gxb = Gf + (size_t)NF * 1024;             // 64 * 1024 floats

    prep_kernel<<<GF_BLOCKS + B_DIM, 1024, 0, stream>>>(f, x, Wih0, bih0, bhh0,
                                                        Gf, Gxb);
    lstm_pipeline<<<B_DIM, 768, 0, stream>>>(Gf, Gxb, Whh0, Whr0,
                                             Wih1, Whh1, bih1, bhh1, Whr1,
                                             Wih2, Whh2, bih2, bhh2, Whr2,
                                             out);
}